// Round 1
// 258.448 us; speedup vs baseline: 1.0490x; 1.0490x over previous
//
#include <hip/hip_runtime.h>

// VQ: z [16384,512] f32, emb [8192,512] f32
// outputs (flat f32): z_q [8388608], loss [1], idx [16384], var [1]

#define BT   16384
#define DIMS 512
#define NE   8192
#define NS   4                       // n-splits
#define BN   256
#define NTPB (NE / NS / BN)          // n-tiles per block = 8
#define NSTEPS 64                    // NTPB * DIMS/64 flat K-steps

// out layout (float elements)
#define LOSS_OFF 8388608
#define IDX_OFF  8388609
#define V_OFF    8404993

// ws layout (bytes)
#define BEST_OFF  0         // u64[16384]
#define ENORM_OFF 131072    // f32[8192]
#define SUMS_OFF  163840    // double[3]
#define CNT_OFF   163864    // unsigned

typedef __attribute__((ext_vector_type(8))) short short8;
typedef __attribute__((ext_vector_type(4))) float floatx4;

#define AS1(p) ((const __attribute__((address_space(1))) void*)(p))
#define AS3(p) ((__attribute__((address_space(3))) void*)(p))

__device__ __forceinline__ unsigned f2bf(float f) {
    unsigned u = __builtin_bit_cast(unsigned, f);
    u += 0x7FFFu + ((u >> 16) & 1u);          // RNE
    return u >> 16;
}

// fused prep: emb->bf16 + ||e||^2 (blocks 0..NE/4), z->bf16 (rest), init best/sums/counter
__global__ __launch_bounds__(256) void prep_kernel(
    const float* __restrict__ z, const float* __restrict__ emb,
    ushort* __restrict__ zh, ushort* __restrict__ ehh,
    float* __restrict__ enorm, unsigned long long* __restrict__ best,
    double* __restrict__ sums, unsigned* __restrict__ counter)
{
    const int lane = threadIdx.x & 63, w = threadIdx.x >> 6;
    const int b = blockIdx.x;
    if (b < NE / 4) {
        const int row = b * 4 + w;
        const float4* p = (const float4*)(emb + (size_t)row * DIMS + lane * 8);
        float4 a = p[0], bb = p[1];
        uint4 h;
        h.x = f2bf(a.x) | (f2bf(a.y) << 16);
        h.y = f2bf(a.z) | (f2bf(a.w) << 16);
        h.z = f2bf(bb.x) | (f2bf(bb.y) << 16);
        h.w = f2bf(bb.z) | (f2bf(bb.w) << 16);
        *(uint4*)(ehh + (size_t)row * DIMS + lane * 8) = h;
        float s = a.x*a.x + a.y*a.y + a.z*a.z + a.w*a.w
                + bb.x*bb.x + bb.y*bb.y + bb.z*bb.z + bb.w*bb.w;
        #pragma unroll
        for (int off = 32; off > 0; off >>= 1) s += __shfl_down(s, off, 64);
        if (lane == 0) enorm[row] = s;
    } else {
        const int row = (b - NE / 4) * 4 + w;
        const float4* p = (const float4*)(z + (size_t)row * DIMS + lane * 8);
        float4 a = p[0], bb = p[1];
        uint4 h;
        h.x = f2bf(a.x) | (f2bf(a.y) << 16);
        h.y = f2bf(a.z) | (f2bf(a.w) << 16);
        h.z = f2bf(bb.x) | (f2bf(bb.y) << 16);
        h.w = f2bf(bb.z) | (f2bf(bb.w) << 16);
        *(uint4*)(zh + (size_t)row * DIMS + lane * 8) = h;
    }
    const int gid = b * 256 + threadIdx.x;
    if (gid < BT) best[gid] = 0xFFFFFFFFFFFFFFFFULL;
    if (gid == 0) { sums[0] = 0.0; sums[1] = 0.0; sums[2] = 0.0; *counter = 0u; }
}

// 256x256-tile 8-wave 8-phase counted-vmcnt argmin GEMM (T3+T4+T5 port).
// 8 waves = 4M x 2N, per-wave 64x128 -> acc[4][8] (128 VGPR), BK=64.
// LDS: double-buffered A/B tiles (128KB) + enorm cache (8KB).
// Flat K-step stream s=0..63 (nt = s>>3, k0 = (s&7)*64) -> pipeline never
// drains at nt boundaries. Per tile: 4 phases x {ds_read, stage 1 half-tile,
// barrier, lgkmcnt(0), 16 MFMA, barrier}; boundary waits s_waitcnt vmcnt(4)
// (A of tile s+2 stays in flight). Stage-target safety: B(s+1) -> opposite
// buffer; A(s+2) -> same buffer, but A frags are fully consumed at phase 0
// and A stages issue at phases 2/3 (>=1 barrier after the reads).
// LDS addressing = round-4-proven conflict-free scheme verbatim: row-major
// [row][64 ushorts], staged lane l covers row l>>3, physical chunk l&7 <-
// logical chunk (l&7)^(l>>3); frag reads at px = (kk*4+quad)^(l15&7).
// Accumulation order (k0 asc, kk asc) identical to previous kernel ->
// bitwise-identical scores -> identical argmin. Ascending-n strict-< =
// numpy first-occurrence tie-break; cross-split merge via packed atomicMin.

#define LOADB(AB_, NJ0)                                                        \
    _Pragma("unroll")                                                          \
    for (int j2 = 0; j2 < 2; j2++) {                                           \
        b[j2][0] = *(const short8*)&lds[16384u + (AB_) + bro + ((NJ0) + j2) * 1024 + pxo0]; \
        b[j2][1] = *(const short8*)&lds[16384u + (AB_) + bro + ((NJ0) + j2) * 1024 + pxo1]; \
    }

#define PHASE_MID(NJ0)                                                         \
    __builtin_amdgcn_sched_barrier(0);                                         \
    __builtin_amdgcn_s_barrier();                                              \
    asm volatile("s_waitcnt lgkmcnt(0)" ::: "memory");                         \
    __builtin_amdgcn_sched_barrier(0);                                         \
    __builtin_amdgcn_s_setprio(1);                                             \
    _Pragma("unroll")                                                          \
    for (int kk = 0; kk < 2; kk++)                                             \
        _Pragma("unroll")                                                      \
        for (int j2 = 0; j2 < 2; j2++)                                         \
            _Pragma("unroll")                                                  \
            for (int mi = 0; mi < 4; mi++)                                     \
                acc[mi][(NJ0) + j2] = __builtin_amdgcn_mfma_f32_16x16x32_bf16( \
                    a[mi][kk], b[j2][kk], acc[mi][(NJ0) + j2], 0, 0, 0);       \
    __builtin_amdgcn_s_setprio(0);

#define STAGE_A(SA_, H_) do {                                                  \
    const int sa_ = (SA_);                                                     \
    if (sa_ < NSTEPS) {                                                        \
        const int k0_ = (sa_ & 7) * 64;                                        \
        const unsigned al_ = (unsigned)(sa_ & 1) * 32768u                      \
                           + (unsigned)((((H_) * 128) + w * 8) * 64);          \
        const ushort* g_ = zA + (size_t)((H_) * 128) * DIMS + soff + k0_;      \
        __builtin_amdgcn_global_load_lds(AS1(g_), AS3(&lds[al_]), 16, 0, 0);   \
        __builtin_amdgcn_global_load_lds(AS1(g_ + (size_t)64 * DIMS),          \
                                         AS3(&lds[al_ + 64 * 64]), 16, 0, 0);  \
    }                                                                          \
} while (0)

#define STAGE_B(SB_, H_) do {                                                  \
    const int sb_ = (SB_);                                                     \
    if (sb_ < NSTEPS) {                                                        \
        const int k0_ = (sb_ & 7) * 64;                                        \
        const unsigned bl_ = 16384u + (unsigned)(sb_ & 1) * 32768u             \
                           + (unsigned)((((H_) * 128) + w * 8) * 64);          \
        const ushort* g_ = eh + (size_t)(nsN + (sb_ >> 3) * 256 + (H_) * 128) * DIMS \
                         + soff + k0_;                                         \
        __builtin_amdgcn_global_load_lds(AS1(g_), AS3(&lds[bl_]), 16, 0, 0);   \
        __builtin_amdgcn_global_load_lds(AS1(g_ + (size_t)64 * DIMS),          \
                                         AS3(&lds[bl_ + 64 * 64]), 16, 0, 0);  \
    }                                                                          \
} while (0)

// TM_: 0 -> vmcnt(4) (steady), 1 -> vmcnt(0) (final fill), 2 -> none (last)
#define STEP(S_, AB_, TM_) do {                                                \
    const int s_ = (S_);                                                       \
    short8 a[4][2], b[2][2];                                                   \
    /* phase 0: A frags (held all tile) + B nj{0,1}; stage B(s+1) half0 */     \
    _Pragma("unroll")                                                          \
    for (int mi = 0; mi < 4; mi++) {                                           \
        a[mi][0] = *(const short8*)&lds[(AB_) + aro + mi * 1024 + pxo0];       \
        a[mi][1] = *(const short8*)&lds[(AB_) + aro + mi * 1024 + pxo1];       \
    }                                                                          \
    LOADB(AB_, 0)                                                              \
    STAGE_B(s_ + 1, 0);                                                        \
    PHASE_MID(0)                                                               \
    __builtin_amdgcn_s_barrier();                                              \
    /* phase 1: B nj{2,3}; stage B(s+1) half1 */                               \
    LOADB(AB_, 2)                                                              \
    STAGE_B(s_ + 1, 1);                                                        \
    PHASE_MID(2)                                                               \
    __builtin_amdgcn_s_barrier();                                              \
    /* phase 2: B nj{4,5}; stage A(s+2) half0 (A of this buf consumed @p0) */  \
    LOADB(AB_, 4)                                                              \
    STAGE_A(s_ + 2, 0);                                                        \
    PHASE_MID(4)                                                               \
    __builtin_amdgcn_s_barrier();                                              \
    /* phase 3: B nj{6,7}; stage A(s+2) half1; counted boundary wait */        \
    LOADB(AB_, 6)                                                              \
    STAGE_A(s_ + 2, 1);                                                        \
    PHASE_MID(6)                                                               \
    if ((TM_) == 0) asm volatile("s_waitcnt vmcnt(4)" ::: "memory");           \
    else if ((TM_) == 1) asm volatile("s_waitcnt vmcnt(0)" ::: "memory");      \
    __builtin_amdgcn_s_barrier();                                              \
} while (0)

__global__ __launch_bounds__(512, 2) void argmin_mfma(
    const ushort* __restrict__ zh, const ushort* __restrict__ eh,
    const float* __restrict__ enorm, unsigned long long* __restrict__ best)
{
    // A: [2 bufs][256][64] @0/@32768, B: same @16384/@49152 (ushort idx),
    // enorm cache: 2048 f32 @65536. Total 139264 B.
    __shared__ __align__(16) ushort lds[69632];
    float* elds = (float*)&lds[65536];

    const int t = threadIdx.x;
    const int w = t >> 6, lane = t & 63;
    const int quad = lane >> 4, l15 = lane & 15;

    // XCD-pairing swizzle (bijective, 256 blocks): xcd pair <-> ns split so
    // each XCD's 32 resident blocks share one 2MB B-panel in its L2.
    const int d = blockIdx.x;
    const int xcd = d & 7, slot = d >> 3;
    const int ns = xcd >> 1;
    const int mt = slot * 2 + (xcd & 1);
    const int m0 = mt * 256;
    const int nsN = ns * (NTPB * BN);         // 2048 * ns

    const int wrow = (w & 3) * 64;            // wave row base in A tile
    const int wcol = (w >> 2) * 128;          // wave col base in B tile

    // enorm -> LDS once (epilogue must NOT issue global loads: they would
    // force a vmcnt drain past the in-flight staging queue)
    {
        float4 v = *(const float4*)(enorm + nsN + t * 4);
        *(float4*)(elds + t * 4) = v;
    }
    __syncthreads();

    // staging lane geometry (pre-swizzled global source, linear LDS dest)
    const int l8 = lane >> 3, c8 = lane & 7;
    const int chunk = c8 ^ l8;
    const int soff = (w * 8 + l8) * DIMS + chunk * 8;
    const ushort* zA = zh + (size_t)m0 * DIMS;

    // frag-read physical chunk offsets (ushorts): (kk*4+quad)^(l15&7) * 8
    const int pxo0 = (quad ^ (l15 & 7)) * 8;
    const int pxo1 = ((4 + quad) ^ (l15 & 7)) * 8;
    const int aro = (wrow + l15) * 64;
    const int bro = (wcol + l15) * 64;

    floatx4 acc[4][8];
    #pragma unroll
    for (int mi = 0; mi < 4; mi++)
        #pragma unroll
        for (int nj = 0; nj < 8; nj++)
            acc[mi][nj] = (floatx4){0.f, 0.f, 0.f, 0.f};

    float bs[16];
    int   bn_[16];
    #pragma unroll
    for (int k = 0; k < 16; k++) { bs[k] = 3.4e38f; bn_[k] = 0; }

    // prologue: A(0), B(0), A(1) staged; wait tile0 complete (A(1) in flight)
    STAGE_A(0, 0); STAGE_A(0, 1);
    STAGE_B(0, 0); STAGE_B(0, 1);
    STAGE_A(1, 0); STAGE_A(1, 1);
    asm volatile("s_waitcnt vmcnt(4)" ::: "memory");
    __builtin_amdgcn_s_barrier();

    for (int sp = 0; sp < NSTEPS; sp += 2) {
        const int tm1 = (sp != NSTEPS - 2) ? 0 : 1;
        const int tm2 = (sp != NSTEPS - 2) ? 0 : 2;
        STEP(sp, 0u, tm1);
        STEP(sp + 1, 32768u, tm2);

        if ((sp & 7) == 6) {
            // n-tile finished: fold scores into running best, reset acc.
            // C/D frag: col = l15 (n), row = quad*4 + r (m).
            const int nt = sp >> 3;
            const int ebase = nt * 256 + wcol + l15;
            const int nbase = nsN + nt * 256 + wcol + l15;
            #pragma unroll
            for (int nj = 0; nj < 8; nj++) {          // nj asc = n asc
                const float en = elds[ebase + nj * 16];
                const int n = nbase + nj * 16;
                #pragma unroll
                for (int mi = 0; mi < 4; mi++) {
                    #pragma unroll
                    for (int r = 0; r < 4; r++) {
                        const int k = mi * 4 + r;
                        const float sc = fmaf(-2.0f, acc[mi][nj][r], en);
                        if (sc < bs[k]) { bs[k] = sc; bn_[k] = n; }
                    }
                    acc[mi][nj] = (floatx4){0.f, 0.f, 0.f, 0.f};
                }
            }
        }
    }

    // once per block: pack, shfl-min over l15 group, atomicMin across splits
    #pragma unroll
    for (int mi = 0; mi < 4; mi++)
        #pragma unroll
        for (int r = 0; r < 4; r++) {
            const int k = mi * 4 + r;
            unsigned su = __builtin_bit_cast(unsigned, bs[k]);
            su = (su & 0x80000000u) ? ~su : (su | 0x80000000u);  // order-preserving
            unsigned long long key = ((unsigned long long)su << 32) | (unsigned)bn_[k];
            #pragma unroll
            for (int off = 1; off < 16; off <<= 1) {
                unsigned long long o = __shfl_xor(key, off, 64);
                key = (o < key) ? o : key;
            }
            if (l15 == 0) atomicMin(&best[m0 + wrow + mi * 16 + quad * 4 + r], key);
        }
}

// one block per 32 rows: idx from packed keys, gather z_q, loss + idx stats;
// last block to finish runs the finalize.
__global__ __launch_bounds__(256) void gather_loss_kernel(
    const float* __restrict__ z, const float* __restrict__ emb,
    const unsigned long long* __restrict__ best,
    float* __restrict__ out, double* __restrict__ sums, unsigned* __restrict__ counter)
{
    __shared__ int sIdx[32];
    __shared__ double red[4];
    const int t = threadIdx.x;
    const int row0 = blockIdx.x * 32;
    double myIdxSum = 0.0, myIdxSq = 0.0;
    if (t < 32) {
        int row = row0 + t;
        int idx = (int)(unsigned)(best[row] & 0xFFFFFFFFULL);
        sIdx[t] = idx;
        out[IDX_OFF + row] = (float)idx;
        myIdxSum = (double)idx;
        myIdxSq = (double)idx * (double)idx;
    }
    __syncthreads();
    double acc = 0.0;
    #pragma unroll 4
    for (int i = 0; i < 16; i++) {
        int e = i * 1024 + t * 4;        // 32 rows x 512 = 16384 elems per block
        int rl = e >> 9;
        int c = e & 511;
        int idx = sIdx[rl];
        float4 zv = *(const float4*)(z + (size_t)(row0 + rl) * DIMS + c);
        float4 ev = *(const float4*)(emb + (size_t)idx * DIMS + c);
        *(float4*)(out + (size_t)(row0 + rl) * DIMS + c) = ev;  // z_q_st value == z_q
        float dx = zv.x - ev.x, dy = zv.y - ev.y;
        float dz = zv.z - ev.z, dw = zv.w - ev.w;
        acc += (double)(dx * dx + dy * dy) + (double)(dz * dz + dw * dw);
    }
    const int lane = t & 63, wv = t >> 6;
    #pragma unroll
    for (int off = 32; off > 0; off >>= 1) {
        acc      += __shfl_down(acc, off, 64);
        myIdxSum += __shfl_down(myIdxSum, off, 64);
        myIdxSq  += __shfl_down(myIdxSq, off, 64);
    }
    if (lane == 0) red[wv] = acc;
    __syncthreads();
    if (t == 0) {
        double tot = red[0] + red[1] + red[2] + red[3];
        atomicAdd(&sums[0], tot);
        atomicAdd(&sums[1], myIdxSum);   // wave 0 held all idx stats
        atomicAdd(&sums[2], myIdxSq);
        __threadfence();
        unsigned old = atomicAdd(counter, 1u);
        if (old == gridDim.x - 1) {
            __threadfence();
            double s0 = atomicAdd(&sums[0], 0.0);
            double s1 = atomicAdd(&sums[1], 0.0);
            double s2 = atomicAdd(&sums[2], 0.0);
            out[LOSS_OFF] = (float)(1.25 * s0 / (double)((size_t)BT * DIMS));
            double m = s1 / (double)BT;
            out[V_OFF] = (float)(s2 / (double)BT - m * m);
        }
    }
}

extern "C" void kernel_launch(void* const* d_in, const int* in_sizes, int n_in,
                              void* d_out, int out_size, void* d_ws, size_t ws_size,
                              hipStream_t stream) {
    const float* z = (const float*)d_in[0];
    const float* emb = (const float*)d_in[1];
    float* out = (float*)d_out;
    char* ws = (char*)d_ws;
    unsigned long long* best = (unsigned long long*)(ws + BEST_OFF);
    float* enorm  = (float*)(ws + ENORM_OFF);
    double* sums  = (double*)(ws + SUMS_OFF);
    unsigned* counter = (unsigned*)(ws + CNT_OFF);

    // bf16 scratch in the z_q region of out (fully overwritten by gather at the end)
    ushort* zh = (ushort*)out;
    ushort* ehh = zh + (size_t)BT * DIMS;

    hipLaunchKernelGGL(prep_kernel, dim3(NE / 4 + BT / 4), dim3(256), 0, stream,
                       z, emb, zh, ehh, enorm, best, sums, counter);
    hipLaunchKernelGGL(argmin_mfma, dim3(256), dim3(512), 0, stream,
                       zh, ehh, enorm, best);
    hipLaunchKernelGGL(gather_loss_kernel, dim3(BT / 32), dim3(256), 0, stream,
                       z, emb, best, out, sums, counter);
}

// Round 2
// 257.962 us; speedup vs baseline: 1.0509x; 1.0019x over previous
//
#include <hip/hip_runtime.h>

// VQ: z [16384,512] f32, emb [8192,512] f32
// outputs (flat f32): z_q [8388608], loss [1], idx [16384], var [1]

#define BT   16384
#define DIMS 512
#define NE   8192
#define NS   4                       // n-splits
#define BN   256
#define NTPB (NE / NS / BN)          // n-tiles per block = 8
#define NSTEPS 64                    // NTPB * DIMS/64 flat K-steps

// out layout (float elements)
#define LOSS_OFF 8388608
#define IDX_OFF  8388609
#define V_OFF    8404993

// ws layout (bytes)
#define BEST_OFF  0         // u64[16384]
#define ENORM_OFF 131072    // f32[8192]
#define SUMS_OFF  163840    // double[3]
#define CNT_OFF   163864    // unsigned

typedef __attribute__((ext_vector_type(8))) short short8;
typedef __attribute__((ext_vector_type(4))) float floatx4;

#define AS1(p) ((const __attribute__((address_space(1))) void*)(p))
#define AS3(p) ((__attribute__((address_space(3))) void*)(p))

__device__ __forceinline__ unsigned f2bf(float f) {
    unsigned u = __builtin_bit_cast(unsigned, f);
    u += 0x7FFFu + ((u >> 16) & 1u);          // RNE
    return u >> 16;
}

// fused prep: emb->bf16 + ||e||^2 (blocks 0..NE/4), z->bf16 (rest), init best/sums/counter
__global__ __launch_bounds__(256) void prep_kernel(
    const float* __restrict__ z, const float* __restrict__ emb,
    ushort* __restrict__ zh, ushort* __restrict__ ehh,
    float* __restrict__ enorm, unsigned long long* __restrict__ best,
    double* __restrict__ sums, unsigned* __restrict__ counter)
{
    const int lane = threadIdx.x & 63, w = threadIdx.x >> 6;
    const int b = blockIdx.x;
    if (b < NE / 4) {
        const int row = b * 4 + w;
        const float4* p = (const float4*)(emb + (size_t)row * DIMS + lane * 8);
        float4 a = p[0], bb = p[1];
        uint4 h;
        h.x = f2bf(a.x) | (f2bf(a.y) << 16);
        h.y = f2bf(a.z) | (f2bf(a.w) << 16);
        h.z = f2bf(bb.x) | (f2bf(bb.y) << 16);
        h.w = f2bf(bb.z) | (f2bf(bb.w) << 16);
        *(uint4*)(ehh + (size_t)row * DIMS + lane * 8) = h;
        float s = a.x*a.x + a.y*a.y + a.z*a.z + a.w*a.w
                + bb.x*bb.x + bb.y*bb.y + bb.z*bb.z + bb.w*bb.w;
        #pragma unroll
        for (int off = 32; off > 0; off >>= 1) s += __shfl_down(s, off, 64);
        if (lane == 0) enorm[row] = s;
    } else {
        const int row = (b - NE / 4) * 4 + w;
        const float4* p = (const float4*)(z + (size_t)row * DIMS + lane * 8);
        float4 a = p[0], bb = p[1];
        uint4 h;
        h.x = f2bf(a.x) | (f2bf(a.y) << 16);
        h.y = f2bf(a.z) | (f2bf(a.w) << 16);
        h.z = f2bf(bb.x) | (f2bf(bb.y) << 16);
        h.w = f2bf(bb.z) | (f2bf(bb.w) << 16);
        *(uint4*)(zh + (size_t)row * DIMS + lane * 8) = h;
    }
    const int gid = b * 256 + threadIdx.x;
    if (gid < BT) best[gid] = 0xFFFFFFFFFFFFFFFFULL;
    if (gid == 0) { sums[0] = 0.0; sums[1] = 0.0; sums[2] = 0.0; *counter = 0u; }
}

// 256x256-tile 8-wave 8-phase counted-vmcnt argmin GEMM — asm-hardened.
// CHANGE vs prior round: all hot-loop LDS frag reads are inline-asm
// ds_read_b128 (and fold enorm reads asm ds_read_b32).  Rationale: C++
// reads of lds[] alias the global_load_lds LDS-writes, entitling hipcc to
// insert s_waitcnt vmcnt(0) before every phase's read cluster — which
// silently degrades the counted-vmcnt pipeline to drain-per-phase (and
// explains the measured equality with the old drain-style kernel).  asm
// reads are outside the compiler's alias model; ordering is enforced
// manually per rule #18: lgkmcnt(0) + sched_barrier(0) before each MFMA
// cluster, and the only VMEM wait in the loop is our vmcnt(4).
// Phase read balance is now 8/8/4/4 (A kk1 frags moved to phase 1), which
// keeps the A LDS region fully consumed one barrier before the phase-2
// A(s+2) restage begins (race-free by barrier ordering).
// Numerics: accumulation order per acc is kk0 then kk1, nj/n ascending —
// bitwise-identical scores and tie-break vs previous rounds.

__device__ __forceinline__ void dsr_fence() {
    asm volatile("s_waitcnt lgkmcnt(0)" ::: "memory");
    __builtin_amdgcn_sched_barrier(0);
}

#define DSR8(dst, IDX) do {                                                    \
    unsigned a_ = (unsigned)(size_t)AS3(&lds[IDX]);                            \
    asm volatile("ds_read_b128 %0, %1" : "=v"(dst) : "v"(a_));                 \
} while (0)

#define PH_SYNC()                                                              \
    __builtin_amdgcn_sched_barrier(0);                                         \
    __builtin_amdgcn_s_barrier();                                              \
    dsr_fence();

#define MFMA16(KK, NJ0)                                                        \
    __builtin_amdgcn_s_setprio(1);                                             \
    _Pragma("unroll")                                                          \
    for (int j2 = 0; j2 < 4; j2++)                                             \
        _Pragma("unroll")                                                      \
        for (int mi = 0; mi < 4; mi++)                                         \
            acc[mi][(NJ0) + j2] = __builtin_amdgcn_mfma_f32_16x16x32_bf16(     \
                a[mi][KK], b[j2], acc[mi][(NJ0) + j2], 0, 0, 0);               \
    __builtin_amdgcn_s_setprio(0);

// staging: dest buffer parity from UNclamped step; source addr clamped
// (tail steps re-load valid data into never-read buffers — branchless)
#define STAGE_A(SA_, H_) do {                                                  \
    const int sa_ = (SA_);                                                     \
    const int sc_ = sa_ & 63;                                                  \
    const unsigned al_ = (unsigned)(sa_ & 1) * 32768u                          \
                       + (unsigned)((((H_) * 128) + w * 8) * 64);              \
    const ushort* g_ = zA + (size_t)((H_) * 128) * DIMS + soff                 \
                     + ((sc_ & 7) * 64);                                       \
    __builtin_amdgcn_global_load_lds(AS1(g_), AS3(&lds[al_]), 16, 0, 0);       \
    __builtin_amdgcn_global_load_lds(AS1(g_ + (size_t)64 * DIMS),              \
                                     AS3(&lds[al_ + 64 * 64]), 16, 0, 0);      \
} while (0)

#define STAGE_B(SB_, H_) do {                                                  \
    const int sb_ = (SB_);                                                     \
    const int sc_ = sb_ & 63;                                                  \
    const unsigned bl_ = 16384u + (unsigned)(sb_ & 1) * 32768u                 \
                       + (unsigned)((((H_) * 128) + w * 8) * 64);              \
    const ushort* g_ = eh + (size_t)(nsN + (sc_ >> 3) * 256 + (H_) * 128) * DIMS \
                     + soff + ((sc_ & 7) * 64);                                \
    __builtin_amdgcn_global_load_lds(AS1(g_), AS3(&lds[bl_]), 16, 0, 0);       \
    __builtin_amdgcn_global_load_lds(AS1(g_ + (size_t)64 * DIMS),              \
                                     AS3(&lds[bl_ + 64 * 64]), 16, 0, 0);      \
} while (0)

// TM_: 0 -> vmcnt(4) steady boundary wait, 2 -> none (last step)
#define STEP(S_, AB_, TM_) do {                                                \
    const int s_ = (S_);                                                       \
    short8 a[4][2], b[4];                                                      \
    /* p0: a[kk0] + b nj0-3 kk0 (8 reads); stage B(s+1) h0 */                  \
    _Pragma("unroll") for (int mi = 0; mi < 4; mi++)                           \
        DSR8(a[mi][0], (AB_) + aro + mi * 1024 + pxo0);                        \
    _Pragma("unroll") for (int j2 = 0; j2 < 4; j2++)                           \
        DSR8(b[j2], 16384u + (AB_) + bro + j2 * 1024 + pxo0);                  \
    STAGE_B(s_ + 1, 0);                                                        \
    PH_SYNC(); MFMA16(0, 0);                                                   \
    __builtin_amdgcn_s_barrier();                                              \
    /* p1: a[kk1] + b nj4-7 kk0 (8 reads); stage B(s+1) h1 */                  \
    _Pragma("unroll") for (int mi = 0; mi < 4; mi++)                           \
        DSR8(a[mi][1], (AB_) + aro + mi * 1024 + pxo1);                        \
    _Pragma("unroll") for (int j2 = 0; j2 < 4; j2++)                           \
        DSR8(b[j2], 16384u + (AB_) + bro + (4 + j2) * 1024 + pxo0);            \
    STAGE_B(s_ + 1, 1);                                                        \
    PH_SYNC(); MFMA16(0, 4);                                                   \
    __builtin_amdgcn_s_barrier();                                              \
    /* p2: b nj0-3 kk1 (4 reads); stage A(s+2) h0 (A-LDS consumed @p1) */      \
    _Pragma("unroll") for (int j2 = 0; j2 < 4; j2++)                           \
        DSR8(b[j2], 16384u + (AB_) + bro + j2 * 1024 + pxo1);                  \
    STAGE_A(s_ + 2, 0);                                                        \
    PH_SYNC(); MFMA16(1, 0);                                                   \
    __builtin_amdgcn_s_barrier();                                              \
    /* p3: b nj4-7 kk1 (4 reads); stage A(s+2) h1; counted boundary wait */    \
    _Pragma("unroll") for (int j2 = 0; j2 < 4; j2++)                           \
        DSR8(b[j2], 16384u + (AB_) + bro + (4 + j2) * 1024 + pxo1);            \
    STAGE_A(s_ + 2, 1);                                                        \
    PH_SYNC(); MFMA16(1, 4);                                                   \
    if ((TM_) == 0) asm volatile("s_waitcnt vmcnt(4)" ::: "memory");           \
    __builtin_amdgcn_s_barrier();                                              \
} while (0)

__global__ __launch_bounds__(512, 2) void argmin_mfma(
    const ushort* __restrict__ zh, const ushort* __restrict__ eh,
    const float* __restrict__ enorm, unsigned long long* __restrict__ best)
{
    // ushort-indexed: A0 [0,16384), B0 [16384,32768), A1 [32768,49152),
    // B1 [49152,65536), enorm f32x2048 [65536,69632). 139264 B total.
    __shared__ __align__(16) ushort lds[69632];
    float* elds = (float*)&lds[65536];

    const int t = threadIdx.x;
    const int w = t >> 6, lane = t & 63;
    const int quad = lane >> 4, l15 = lane & 15;

    // XCD-pairing swizzle (bijective, 256 blocks): each XCD's 32 resident
    // blocks share one 2MB B-panel in its L2.
    const int d = blockIdx.x;
    const int xcd = d & 7, slot = d >> 3;
    const int ns = xcd >> 1;
    const int mt = slot * 2 + (xcd & 1);
    const int m0 = mt * 256;
    const int nsN = ns * (NTPB * BN);         // 2048 * ns

    const int wrow = (w & 3) * 64;            // wave row base in A tile
    const int wcol = (w >> 2) * 128;          // wave col base in B tile

    // enorm -> LDS once (fold must not issue tracked global loads)
    {
        float4 v = *(const float4*)(enorm + nsN + t * 4);
        *(float4*)(elds + t * 4) = v;
    }
    __syncthreads();

    // staging lane geometry (pre-swizzled global source, linear LDS dest)
    const int l8 = lane >> 3, c8 = lane & 7;
    const int chunk = c8 ^ l8;
    const int soff = (w * 8 + l8) * DIMS + chunk * 8;
    const ushort* zA = zh + (size_t)m0 * DIMS;

    // frag-read physical chunk offsets (ushorts): (kk*4+quad)^(l15&7) * 8
    const int pxo0 = (quad ^ (l15 & 7)) * 8;
    const int pxo1 = ((4 + quad) ^ (l15 & 7)) * 8;
    const int aro = (wrow + l15) * 64;
    const int bro = (wcol + l15) * 64;

    floatx4 acc[4][8];
    #pragma unroll
    for (int mi = 0; mi < 4; mi++)
        #pragma unroll
        for (int nj = 0; nj < 8; nj++)
            acc[mi][nj] = (floatx4){0.f, 0.f, 0.f, 0.f};

    float bs[16];
    int   bn_[16];
    #pragma unroll
    for (int k = 0; k < 16; k++) { bs[k] = 3.4e38f; bn_[k] = 0; }

    // prologue: A(0), B(0), A(1) staged; per-wave vmcnt(4) + barrier ->
    // all waves' A(0)/B(0) writes landed before anyone proceeds
    STAGE_A(0, 0); STAGE_A(0, 1);
    STAGE_B(0, 0); STAGE_B(0, 1);
    STAGE_A(1, 0); STAGE_A(1, 1);
    asm volatile("s_waitcnt vmcnt(4)" ::: "memory");
    __builtin_amdgcn_s_barrier();

    for (int sp = 0; sp < NSTEPS; sp += 2) {
        STEP(sp, 0u, 0);
        STEP(sp + 1, 32768u, (sp == NSTEPS - 2) ? 2 : 0);

        if ((sp & 7) == 6) {
            // n-tile finished: fold scores into running best, reset acc.
            // C/D frag: col = l15 (n), row = quad*4 + r (m).
            const int nt = sp >> 3;
            const int eb = nt * 256 + wcol + l15;
            const int nbase = nsN + eb;
            float en[8];
            #pragma unroll
            for (int nj = 0; nj < 8; nj++) {
                unsigned a_ = (unsigned)(size_t)AS3(&elds[eb + nj * 16]);
                asm volatile("ds_read_b32 %0, %1" : "=v"(en[nj]) : "v"(a_));
            }
            dsr_fence();
            #pragma unroll
            for (int nj = 0; nj < 8; nj++) {          // nj asc = n asc
                const int n = nbase + nj * 16;
                #pragma unroll
                for (int mi = 0; mi < 4; mi++) {
                    #pragma unroll
                    for (int r = 0; r < 4; r++) {
                        const int k = mi * 4 + r;
                        const float sc = fmaf(-2.0f, acc[mi][nj][r], en[nj]);
                        if (sc < bs[k]) { bs[k] = sc; bn_[k] = n; }
                    }
                    acc[mi][nj] = (floatx4){0.f, 0.f, 0.f, 0.f};
                }
            }
        }
    }

    // once per block: pack, shfl-min over l15 group, atomicMin across splits
    #pragma unroll
    for (int mi = 0; mi < 4; mi++)
        #pragma unroll
        for (int r = 0; r < 4; r++) {
            const int k = mi * 4 + r;
            unsigned su = __builtin_bit_cast(unsigned, bs[k]);
            su = (su & 0x80000000u) ? ~su : (su | 0x80000000u);  // order-preserving
            unsigned long long key = ((unsigned long long)su << 32) | (unsigned)bn_[k];
            #pragma unroll
            for (int off = 1; off < 16; off <<= 1) {
                unsigned long long o = __shfl_xor(key, off, 64);
                key = (o < key) ? o : key;
            }
            if (l15 == 0) atomicMin(&best[m0 + wrow + mi * 16 + quad * 4 + r], key);
        }
}

// one block per 32 rows: idx from packed keys, gather z_q, loss + idx stats;
// last block to finish runs the finalize.
__global__ __launch_bounds__(256) void gather_loss_kernel(
    const float* __restrict__ z, const float* __restrict__ emb,
    const unsigned long long* __restrict__ best,
    float* __restrict__ out, double* __restrict__ sums, unsigned* __restrict__ counter)
{
    __shared__ int sIdx[32];
    __shared__ double red[4];
    const int t = threadIdx.x;
    const int row0 = blockIdx.x * 32;
    double myIdxSum = 0.0, myIdxSq = 0.0;
    if (t < 32) {
        int row = row0 + t;
        int idx = (int)(unsigned)(best[row] & 0xFFFFFFFFULL);
        sIdx[t] = idx;
        out[IDX_OFF + row] = (float)idx;
        myIdxSum = (double)idx;
        myIdxSq = (double)idx * (double)idx;
    }
    __syncthreads();
    double acc = 0.0;
    #pragma unroll 4
    for (int i = 0; i < 16; i++) {
        int e = i * 1024 + t * 4;        // 32 rows x 512 = 16384 elems per block
        int rl = e >> 9;
        int c = e & 511;
        int idx = sIdx[rl];
        float4 zv = *(const float4*)(z + (size_t)(row0 + rl) * DIMS + c);
        float4 ev = *(const float4*)(emb + (size_t)idx * DIMS + c);
        *(float4*)(out + (size_t)(row0 + rl) * DIMS + c) = ev;  // z_q_st value == z_q
        float dx = zv.x - ev.x, dy = zv.y - ev.y;
        float dz = zv.z - ev.z, dw = zv.w - ev.w;
        acc += (double)(dx * dx + dy * dy) + (double)(dz * dz + dw * dw);
    }
    const int lane = t & 63, wv = t >> 6;
    #pragma unroll
    for (int off = 32; off > 0; off >>= 1) {
        acc      += __shfl_down(acc, off, 64);
        myIdxSum += __shfl_down(myIdxSum, off, 64);
        myIdxSq  += __shfl_down(myIdxSq, off, 64);
    }
    if (lane == 0) red[wv] = acc;
    __syncthreads();
    if (t == 0) {
        double tot = red[0] + red[1] + red[2] + red[3];
        atomicAdd(&sums[0], tot);
        atomicAdd(&sums[1], myIdxSum);   // wave 0 held all idx stats
        atomicAdd(&sums[2], myIdxSq);
        __threadfence();
        unsigned old = atomicAdd(counter, 1u);
        if (old == gridDim.x - 1) {
            __threadfence();
            double s0 = atomicAdd(&sums[0], 0.0);
            double s1 = atomicAdd(&sums[1], 0.0);
            double s2 = atomicAdd(&sums[2], 0.0);
            out[LOSS_OFF] = (float)(1.25 * s0 / (double)((size_t)BT * DIMS));
            double m = s1 / (double)BT;
            out[V_OFF] = (float)(s2 / (double)BT - m * m);
        }
    }
}

extern "C" void kernel_launch(void* const* d_in, const int* in_sizes, int n_in,
                              void* d_out, int out_size, void* d_ws, size_t ws_size,
                              hipStream_t stream) {
    const float* z = (const float*)d_in[0];
    const float* emb = (const float*)d_in[1];
    float* out = (float*)d_out;
    char* ws = (char*)d_ws;
    unsigned long long* best = (unsigned long long*)(ws + BEST_OFF);
    float* enorm  = (float*)(ws + ENORM_OFF);
    double* sums  = (double*)(ws + SUMS_OFF);
    unsigned* counter = (unsigned*)(ws + CNT_OFF);

    // bf16 scratch in the z_q region of out (fully overwritten by gather at the end)
    ushort* zh = (ushort*)out;
    ushort* ehh = zh + (size_t)BT * DIMS;

    hipLaunchKernelGGL(prep_kernel, dim3(NE / 4 + BT / 4), dim3(256), 0, stream,
                       z, emb, zh, ehh, enorm, best, sums, counter);
    hipLaunchKernelGGL(argmin_mfma, dim3(256), dim3(512), 0, stream,
                       zh, ehh, enorm, best);
    hipLaunchKernelGGL(gather_loss_kernel, dim3(BT / 32), dim3(256), 0, stream,
                       z, emb, best, out, sums, counter);
}

// Round 3
// 244.176 us; speedup vs baseline: 1.1103x; 1.0565x over previous
//
#include <hip/hip_runtime.h>

// VQ: z [16384,512] f32, emb [8192,512] f32
// outputs (flat f32): z_q [8388608], loss [1], idx [16384], var [1]

#define BT   16384
#define DIMS 512
#define NE   8192
#define NS   4                       // n-splits
#define BN   256
#define NTPB (NE / NS / BN)          // n-tiles per block = 8
#define NSTEPS 64                    // NTPB * DIMS/64 flat K-steps

// out layout (float elements)
#define LOSS_OFF 8388608
#define IDX_OFF  8388609
#define V_OFF    8404993

// ws layout (bytes)
#define BEST_OFF  0         // u64[16384]
#define ENORM_OFF 131072    // f32[8192]
#define SUMS_OFF  163840    // double[3]
#define CNT_OFF   163864    // unsigned

typedef __attribute__((ext_vector_type(8))) short short8;
typedef __attribute__((ext_vector_type(4))) float floatx4;

#define AS1(p) ((const __attribute__((address_space(1))) void*)(p))
#define AS3(p) ((__attribute__((address_space(3))) void*)(p))

__device__ __forceinline__ unsigned f2bf(float f) {
    unsigned u = __builtin_bit_cast(unsigned, f);
    u += 0x7FFFu + ((u >> 16) & 1u);          // RNE
    return u >> 16;
}

// fused prep: emb->bf16 + ||e||^2 (blocks 0..NE/4), z->bf16 (rest), init best/sums/counter
__global__ __launch_bounds__(256) void prep_kernel(
    const float* __restrict__ z, const float* __restrict__ emb,
    ushort* __restrict__ zh, ushort* __restrict__ ehh,
    float* __restrict__ enorm, unsigned long long* __restrict__ best,
    double* __restrict__ sums, unsigned* __restrict__ counter)
{
    const int lane = threadIdx.x & 63, w = threadIdx.x >> 6;
    const int b = blockIdx.x;
    if (b < NE / 4) {
        const int row = b * 4 + w;
        const float4* p = (const float4*)(emb + (size_t)row * DIMS + lane * 8);
        float4 a = p[0], bb = p[1];
        uint4 h;
        h.x = f2bf(a.x) | (f2bf(a.y) << 16);
        h.y = f2bf(a.z) | (f2bf(a.w) << 16);
        h.z = f2bf(bb.x) | (f2bf(bb.y) << 16);
        h.w = f2bf(bb.z) | (f2bf(bb.w) << 16);
        *(uint4*)(ehh + (size_t)row * DIMS + lane * 8) = h;
        float s = a.x*a.x + a.y*a.y + a.z*a.z + a.w*a.w
                + bb.x*bb.x + bb.y*bb.y + bb.z*bb.z + bb.w*bb.w;
        #pragma unroll
        for (int off = 32; off > 0; off >>= 1) s += __shfl_down(s, off, 64);
        if (lane == 0) enorm[row] = s;
    } else {
        const int row = (b - NE / 4) * 4 + w;
        const float4* p = (const float4*)(z + (size_t)row * DIMS + lane * 8);
        float4 a = p[0], bb = p[1];
        uint4 h;
        h.x = f2bf(a.x) | (f2bf(a.y) << 16);
        h.y = f2bf(a.z) | (f2bf(a.w) << 16);
        h.z = f2bf(bb.x) | (f2bf(bb.y) << 16);
        h.w = f2bf(bb.z) | (f2bf(bb.w) << 16);
        *(uint4*)(zh + (size_t)row * DIMS + lane * 8) = h;
    }
    const int gid = b * 256 + threadIdx.x;
    if (gid < BT) best[gid] = 0xFFFFFFFFFFFFFFFFULL;
    if (gid == 0) { sums[0] = 0.0; sums[1] = 0.0; sums[2] = 0.0; *counter = 0u; }
}

// 256x256-tile 8-wave argmin GEMM — 2-barrier/step, counted-lgkm interleave.
// CHANGE vs prior round: the 4-phase lockstep (8 barriers/step, full
// lgkmcnt(0) drain before every MFMA cluster) serialized the LDS pipe
// against the MFMA pipe (measured: step time 5160 cy ~= LDS-busy 2330 +
// MFMA-busy 2490).  Hazard analysis shows only TWO barriers per step are
// required: (1) after the last A-frag read, before the A(s+2) restage into
// the SAME A buffer; (2) at the step boundary (with vmcnt(4)) gating the
// B(s+1)/A(s+2) buffer swap.  B stages always target the opposite buffer.
// All other barriers removed -> waves skew, LDS service overlaps MFMA.
// Within a wave, each 4-MFMA cluster waits only for its own frags via
// counted lgkm (DS completes in-order), pinned with sched_barrier(0)
// (rule #18).  Register envelope unchanged: a[4]+b[8] = 48 frag VGPRs
// (was a[4][2]+b[4]) -- stays at the 128 VGPR + 128 AGPR = 256/wave cliff.
// Per-acc accumulation order still (k0 asc, kk0 then kk1) -> bitwise-
// identical scores, tie-break, absmax vs previous rounds.

__device__ __forceinline__ void dsr_fence() {
    asm volatile("s_waitcnt lgkmcnt(0)" ::: "memory");
    __builtin_amdgcn_sched_barrier(0);
}

#define DSR8(dst, IDX) do {                                                    \
    unsigned addr_ = (unsigned)(size_t)AS3(&lds[IDX]);                         \
    asm volatile("ds_read_b128 %0, %1" : "=v"(dst) : "v"(addr_));              \
} while (0)

#define LGK(N_) do {                                                           \
    asm volatile("s_waitcnt lgkmcnt(" #N_ ")" ::: "memory");                   \
    __builtin_amdgcn_sched_barrier(0);                                         \
} while (0)

#define CL4(J_, BIDX_)                                                         \
    _Pragma("unroll")                                                          \
    for (int mi = 0; mi < 4; mi++)                                             \
        acc[mi][J_] = __builtin_amdgcn_mfma_f32_16x16x32_bf16(                 \
            a[mi], b[BIDX_], acc[mi][J_], 0, 0, 0);

// staging: dest buffer parity from UNclamped step; source addr clamped
// (tail steps re-load valid data into never-read buffers — branchless)
#define STAGE_A(SA_, H_) do {                                                  \
    const int sa_ = (SA_);                                                     \
    const int sc_ = sa_ & 63;                                                  \
    const unsigned al_ = (unsigned)(sa_ & 1) * 32768u                          \
                       + (unsigned)((((H_) * 128) + w * 8) * 64);              \
    const ushort* g_ = zA + (size_t)((H_) * 128) * DIMS + soff                 \
                     + ((sc_ & 7) * 64);                                       \
    __builtin_amdgcn_global_load_lds(AS1(g_), AS3(&lds[al_]), 16, 0, 0);       \
    __builtin_amdgcn_global_load_lds(AS1(g_ + (size_t)64 * DIMS),              \
                                     AS3(&lds[al_ + 64 * 64]), 16, 0, 0);      \
} while (0)

#define STAGE_B(SB_, H_) do {                                                  \
    const int sb_ = (SB_);                                                     \
    const int sc_ = sb_ & 63;                                                  \
    const unsigned bl_ = 16384u + (unsigned)(sb_ & 1) * 32768u                 \
                       + (unsigned)((((H_) * 128) + w * 8) * 64);              \
    const ushort* g_ = eh + (size_t)(nsN + (sc_ >> 3) * 256 + (H_) * 128) * DIMS \
                     + soff + ((sc_ & 7) * 64);                                \
    __builtin_amdgcn_global_load_lds(AS1(g_), AS3(&lds[bl_]), 16, 0, 0);       \
    __builtin_amdgcn_global_load_lds(AS1(g_ + (size_t)64 * DIMS),              \
                                     AS3(&lds[bl_ + 64 * 64]), 16, 0, 0);      \
} while (0)

// Per-step DS-queue schedule (in-order completion, per wave):
//   p0 issues r1-r8  = A0-3 kk0, B0-3 kk0;  clusters wait 3/2/1/0
//   p1 issues r9-r16 = B4-7 kk0, B0-3 kk1;  clusters wait 7/6/5/4
//   p2 issues r17-r24= A0-3 kk1, B4-7 kk1;  one wait (4), 16 MFMA
//   BARRIER #1 (all A-frag reads retired -> A(s+2) restage safe)
//   p3: stage A(s+2); clusters wait 3/2/1/0; [vmcnt(4)]; BARRIER #2
// TM_: 0 -> vmcnt(4) steady boundary wait, 2 -> none (last step)
#define STEP(S_, AB_, TM_) do {                                                \
    const int s_ = (S_);                                                       \
    short8 a[4], b[8];                                                         \
    /* p0 */                                                                   \
    _Pragma("unroll") for (int mi = 0; mi < 4; mi++)                           \
        DSR8(a[mi], (AB_) + aro + mi * 1024 + pxo0);                           \
    _Pragma("unroll") for (int j = 0; j < 4; j++)                              \
        DSR8(b[j], 16384u + (AB_) + bro + j * 1024 + pxo0);                    \
    STAGE_B(s_ + 1, 0);                                                        \
    __builtin_amdgcn_s_setprio(1);                                             \
    LGK(3); CL4(0, 0); LGK(2); CL4(1, 1); LGK(1); CL4(2, 2); LGK(0); CL4(3, 3);\
    __builtin_amdgcn_s_setprio(0);                                             \
    /* p1 */                                                                   \
    _Pragma("unroll") for (int j = 0; j < 4; j++)                              \
        DSR8(b[4 + j], 16384u + (AB_) + bro + (4 + j) * 1024 + pxo0);          \
    _Pragma("unroll") for (int j = 0; j < 4; j++)                              \
        DSR8(b[j], 16384u + (AB_) + bro + j * 1024 + pxo1);                    \
    STAGE_B(s_ + 1, 1);                                                        \
    __builtin_amdgcn_s_setprio(1);                                             \
    LGK(7); CL4(4, 4); LGK(6); CL4(5, 5); LGK(5); CL4(6, 6); LGK(4); CL4(7, 7);\
    __builtin_amdgcn_s_setprio(0);                                             \
    /* p2 */                                                                   \
    _Pragma("unroll") for (int mi = 0; mi < 4; mi++)                           \
        DSR8(a[mi], (AB_) + aro + mi * 1024 + pxo1);                           \
    _Pragma("unroll") for (int j = 0; j < 4; j++)                              \
        DSR8(b[4 + j], 16384u + (AB_) + bro + (4 + j) * 1024 + pxo1);          \
    __builtin_amdgcn_s_setprio(1);                                             \
    LGK(4); CL4(0, 0); CL4(1, 1); CL4(2, 2); CL4(3, 3);                        \
    __builtin_amdgcn_s_setprio(0);                                             \
    __builtin_amdgcn_sched_barrier(0);                                         \
    __builtin_amdgcn_s_barrier();           /* A readers done -> restage ok */ \
    /* p3 */                                                                   \
    STAGE_A(s_ + 2, 0); STAGE_A(s_ + 2, 1);                                    \
    __builtin_amdgcn_s_setprio(1);                                             \
    LGK(3); CL4(4, 4); LGK(2); CL4(5, 5); LGK(1); CL4(6, 6); LGK(0); CL4(7, 7);\
    __builtin_amdgcn_s_setprio(0);                                             \
    __builtin_amdgcn_sched_barrier(0);                                         \
    if ((TM_) == 0) asm volatile("s_waitcnt vmcnt(4)" ::: "memory");           \
    __builtin_amdgcn_s_barrier();                                              \
} while (0)

__global__ __launch_bounds__(512, 2) void argmin_mfma(
    const ushort* __restrict__ zh, const ushort* __restrict__ eh,
    const float* __restrict__ enorm, unsigned long long* __restrict__ best)
{
    // ushort-indexed: A0 [0,16384), B0 [16384,32768), A1 [32768,49152),
    // B1 [49152,65536), enorm f32x2048 [65536,69632). 139264 B total.
    __shared__ __align__(16) ushort lds[69632];
    float* elds = (float*)&lds[65536];

    const int t = threadIdx.x;
    const int w = t >> 6, lane = t & 63;
    const int quad = lane >> 4, l15 = lane & 15;

    // XCD-pairing swizzle (bijective, 256 blocks): each XCD's 32 resident
    // blocks share one 2MB B-panel in its L2.
    const int d = blockIdx.x;
    const int xcd = d & 7, slot = d >> 3;
    const int ns = xcd >> 1;
    const int mt = slot * 2 + (xcd & 1);
    const int m0 = mt * 256;
    const int nsN = ns * (NTPB * BN);         // 2048 * ns

    const int wrow = (w & 3) * 64;            // wave row base in A tile
    const int wcol = (w >> 2) * 128;          // wave col base in B tile

    // enorm -> LDS once (fold must not issue tracked global loads)
    {
        float4 v = *(const float4*)(enorm + nsN + t * 4);
        *(float4*)(elds + t * 4) = v;
    }
    __syncthreads();

    // staging lane geometry (pre-swizzled global source, linear LDS dest)
    const int l8 = lane >> 3, c8 = lane & 7;
    const int chunk = c8 ^ l8;
    const int soff = (w * 8 + l8) * DIMS + chunk * 8;
    const ushort* zA = zh + (size_t)m0 * DIMS;

    // frag-read physical chunk offsets (ushorts): (kk*4+quad)^(l15&7) * 8
    const int pxo0 = (quad ^ (l15 & 7)) * 8;
    const int pxo1 = ((4 + quad) ^ (l15 & 7)) * 8;
    const int aro = (wrow + l15) * 64;
    const int bro = (wcol + l15) * 64;

    floatx4 acc[4][8];
    #pragma unroll
    for (int mi = 0; mi < 4; mi++)
        #pragma unroll
        for (int nj = 0; nj < 8; nj++)
            acc[mi][nj] = (floatx4){0.f, 0.f, 0.f, 0.f};

    float bs[16];
    int   bn_[16];
    #pragma unroll
    for (int k = 0; k < 16; k++) { bs[k] = 3.4e38f; bn_[k] = 0; }

    // prologue: A(0), B(0), A(1) staged; vmcnt(4) -> A(0)/B(0) landed,
    // A(1) in flight; barrier
    STAGE_A(0, 0); STAGE_A(0, 1);
    STAGE_B(0, 0); STAGE_B(0, 1);
    STAGE_A(1, 0); STAGE_A(1, 1);
    asm volatile("s_waitcnt vmcnt(4)" ::: "memory");
    __builtin_amdgcn_s_barrier();

    for (int sp = 0; sp < NSTEPS; sp += 2) {
        STEP(sp, 0u, 0);
        STEP(sp + 1, 32768u, (sp == NSTEPS - 2) ? 2 : 0);

        if ((sp & 7) == 6) {
            // n-tile finished: fold scores into running best, reset acc.
            // C/D frag: col = l15 (n), row = quad*4 + r (m).
            const int nt = sp >> 3;
            const int eb = nt * 256 + wcol + l15;
            const int nbase = nsN + eb;
            float en[8];
            #pragma unroll
            for (int nj = 0; nj < 8; nj++) {
                unsigned addr_ = (unsigned)(size_t)AS3(&elds[eb + nj * 16]);
                asm volatile("ds_read_b32 %0, %1" : "=v"(en[nj]) : "v"(addr_));
            }
            dsr_fence();
            #pragma unroll
            for (int nj = 0; nj < 8; nj++) {          // nj asc = n asc
                const int n = nbase + nj * 16;
                #pragma unroll
                for (int mi = 0; mi < 4; mi++) {
                    #pragma unroll
                    for (int r = 0; r < 4; r++) {
                        const int k = mi * 4 + r;
                        const float sc = fmaf(-2.0f, acc[mi][nj][r], en[nj]);
                        if (sc < bs[k]) { bs[k] = sc; bn_[k] = n; }
                    }
                    acc[mi][nj] = (floatx4){0.f, 0.f, 0.f, 0.f};
                }
            }
        }
    }

    // drain tail staging gloads before epilogue/endpgm (once, cheap)
    asm volatile("s_waitcnt vmcnt(0)" ::: "memory");

    // once per block: pack, shfl-min over l15 group, atomicMin across splits
    #pragma unroll
    for (int mi = 0; mi < 4; mi++)
        #pragma unroll
        for (int r = 0; r < 4; r++) {
            const int k = mi * 4 + r;
            unsigned su = __builtin_bit_cast(unsigned, bs[k]);
            su = (su & 0x80000000u) ? ~su : (su | 0x80000000u);  // order-preserving
            unsigned long long key = ((unsigned long long)su << 32) | (unsigned)bn_[k];
            #pragma unroll
            for (int off = 1; off < 16; off <<= 1) {
                unsigned long long o = __shfl_xor(key, off, 64);
                key = (o < key) ? o : key;
            }
            if (l15 == 0) atomicMin(&best[m0 + wrow + mi * 16 + quad * 4 + r], key);
        }
}

// one block per 32 rows: idx from packed keys, gather z_q, loss + idx stats;
// last block to finish runs the finalize.
__global__ __launch_bounds__(256) void gather_loss_kernel(
    const float* __restrict__ z, const float* __restrict__ emb,
    const unsigned long long* __restrict__ best,
    float* __restrict__ out, double* __restrict__ sums, unsigned* __restrict__ counter)
{
    __shared__ int sIdx[32];
    __shared__ double red[4];
    const int t = threadIdx.x;
    const int row0 = blockIdx.x * 32;
    double myIdxSum = 0.0, myIdxSq = 0.0;
    if (t < 32) {
        int row = row0 + t;
        int idx = (int)(unsigned)(best[row] & 0xFFFFFFFFULL);
        sIdx[t] = idx;
        out[IDX_OFF + row] = (float)idx;
        myIdxSum = (double)idx;
        myIdxSq = (double)idx * (double)idx;
    }
    __syncthreads();
    double acc = 0.0;
    #pragma unroll 4
    for (int i = 0; i < 16; i++) {
        int e = i * 1024 + t * 4;        // 32 rows x 512 = 16384 elems per block
        int rl = e >> 9;
        int c = e & 511;
        int idx = sIdx[rl];
        float4 zv = *(const float4*)(z + (size_t)(row0 + rl) * DIMS + c);
        float4 ev = *(const float4*)(emb + (size_t)idx * DIMS + c);
        *(float4*)(out + (size_t)(row0 + rl) * DIMS + c) = ev;  // z_q_st value == z_q
        float dx = zv.x - ev.x, dy = zv.y - ev.y;
        float dz = zv.z - ev.z, dw = zv.w - ev.w;
        acc += (double)(dx * dx + dy * dy) + (double)(dz * dz + dw * dw);
    }
    const int lane = t & 63, wv = t >> 6;
    #pragma unroll
    for (int off = 32; off > 0; off >>= 1) {
        acc      += __shfl_down(acc, off, 64);
        myIdxSum += __shfl_down(myIdxSum, off, 64);
        myIdxSq  += __shfl_down(myIdxSq, off, 64);
    }
    if (lane == 0) red[wv] = acc;
    __syncthreads();
    if (t == 0) {
        double tot = red[0] + red[1] + red[2] + red[3];
        atomicAdd(&sums[0], tot);
        atomicAdd(&sums[1], myIdxSum);   // wave 0 held all idx stats
        atomicAdd(&sums[2], myIdxSq);
        __threadfence();
        unsigned old = atomicAdd(counter, 1u);
        if (old == gridDim.x - 1) {
            __threadfence();
            double s0 = atomicAdd(&sums[0], 0.0);
            double s1 = atomicAdd(&sums[1], 0.0);
            double s2 = atomicAdd(&sums[2], 0.0);
            out[LOSS_OFF] = (float)(1.25 * s0 / (double)((size_t)BT * DIMS));
            double m = s1 / (double)BT;
            out[V_OFF] = (float)(s2 / (double)BT - m * m);
        }
    }
}

extern "C" void kernel_launch(void* const* d_in, const int* in_sizes, int n_in,
                              void* d_out, int out_size, void* d_ws, size_t ws_size,
                              hipStream_t stream) {
    const float* z = (const float*)d_in[0];
    const float* emb = (const float*)d_in[1];
    float* out = (float*)d_out;
    char* ws = (char*)d_ws;
    unsigned long long* best = (unsigned long long*)(ws + BEST_OFF);
    float* enorm  = (float*)(ws + ENORM_OFF);
    double* sums  = (double*)(ws + SUMS_OFF);
    unsigned* counter = (unsigned*)(ws + CNT_OFF);

    // bf16 scratch in the z_q region of out (fully overwritten by gather at the end)
    ushort* zh = (ushort*)out;
    ushort* ehh = zh + (size_t)BT * DIMS;

    hipLaunchKernelGGL(prep_kernel, dim3(NE / 4 + BT / 4), dim3(256), 0, stream,
                       z, emb, zh, ehh, enorm, best, sums, counter);
    hipLaunchKernelGGL(argmin_mfma, dim3(256), dim3(512), 0, stream,
                       zh, ehh, enorm, best);
    hipLaunchKernelGGL(gather_loss_kernel, dim3(BT / 32), dim3(256), 0, stream,
                       z, emb, best, out, sums, counter);
}